// Round 4
// baseline (238.699 us; speedup 1.0000x reference)
//
#include <hip/hip_runtime.h>

// R4: attn main loop made LDS-free. The PV k-permutation is chosen to match
// what each lane already holds from the S^T C-layout (k is a reduction dim -
// any order is legal if A and B agree), so P's C->A transform is a pure
// register repack. l accumulated via a ones-A MFMA. proj/wt/mask/ln unchanged.

typedef __attribute__((ext_vector_type(8))) __bf16 bf16x8;
typedef __attribute__((ext_vector_type(4))) float f32x4;

#if __has_builtin(__builtin_amdgcn_exp2f)
#define EXP2F __builtin_amdgcn_exp2f
#else
#define EXP2F exp2f
#endif

#define QSCALE (0.125f * 1.4426950408889634f)  // fold /sqrt(64) and ln->log2

__device__ __forceinline__ unsigned short f2bf(float f) {
  return __builtin_bit_cast(unsigned short, (__bf16)f);
}
__device__ __forceinline__ unsigned pk2(float a, float b) {
  return (unsigned)f2bf(a) | ((unsigned)f2bf(b) << 16);
}
__device__ __forceinline__ f32x4 mfma16(bf16x8 a, bf16x8 b, f32x4 c) {
  return __builtin_amdgcn_mfma_f32_16x16x32_bf16(a, b, c, 0, 0, 0);
}
__device__ __forceinline__ bf16x8 ld_bf8(const unsigned short* p) {
  return *(const bf16x8*)p;
}
// async global->LDS, 16 B per lane; LDS dst must be wave-uniform base + lane*16
__device__ __forceinline__ void g2l16(const void* g, void* l) {
  __builtin_amdgcn_global_load_lds(
      (const __attribute__((address_space(1))) void*)g,
      (__attribute__((address_space(3))) void*)l, 16, 0, 0);
}

// ---------------------------------------------------------------------------
// Kernel 1: transpose + convert the three 512x512 weight matrices to bf16,
// layout Wt[z][n][k] (n-major) so MFMA B-fragments read contiguous k.
// ---------------------------------------------------------------------------
__global__ __launch_bounds__(256) void wt_kernel(const float* __restrict__ Wq,
                                                 const float* __restrict__ Wk,
                                                 const float* __restrict__ Wv,
                                                 unsigned short* __restrict__ Wt) {
  int idx = blockIdx.x * 256 + threadIdx.x;
  int o = idx * 8;
  int z = o >> 18;
  int rem = o & 262143;
  int n = rem >> 9;
  int k0 = rem & 511;
  const float* W = (z == 0) ? Wq : ((z == 1) ? Wk : Wv);
  unsigned int w[4];
#pragma unroll
  for (int i = 0; i < 4; ++i) {
    unsigned short lo = f2bf(W[(k0 + 2 * i) * 512 + n]);
    unsigned short hi = f2bf(W[(k0 + 2 * i + 1) * 512 + n]);
    w[i] = (unsigned)lo | ((unsigned)hi << 16);
  }
  *(uint4*)(Wt + o) = make_uint4(w[0], w[1], w[2], w[3]);
}

// ---------------------------------------------------------------------------
// Kernel 2: key/query padding masks: sign(|row sum|) of the RAW inputs.
// ---------------------------------------------------------------------------
__global__ __launch_bounds__(256) void mask_kernel(const float* __restrict__ q,
                                                   const float* __restrict__ k,
                                                   float* __restrict__ qmask,
                                                   float* __restrict__ kmask) {
  int w = blockIdx.x * 4 + (threadIdx.x >> 6);
  int lane = threadIdx.x & 63;
  const float* src = (w < 8192) ? q : k;
  int row = w & 8191;
  const float4* p = (const float4*)(src + row * 512);
  float4 v1 = p[lane];
  float4 v2 = p[64 + lane];
  float s = v1.x + v1.y + v1.z + v1.w + v2.x + v2.y + v2.z + v2.w;
#pragma unroll
  for (int off = 32; off > 0; off >>= 1) s += __shfl_xor(s, off);
  if (lane == 0) {
    float m = (s == 0.0f) ? 0.0f : 1.0f;
    if (w < 8192) qmask[row] = m; else kmask[row] = m;
  }
}

// ---------------------------------------------------------------------------
// Kernel 3: QKV projection as m97-style GEMM (unchanged from R3).
// ---------------------------------------------------------------------------
__global__ __launch_bounds__(256, 3) void proj_kernel(
    const float* __restrict__ Xq, const float* __restrict__ Xk,
    const float* __restrict__ Xv, const float* __restrict__ bq,
    const float* __restrict__ bk, const float* __restrict__ bv,
    const unsigned short* __restrict__ Wt, unsigned short* __restrict__ Qb,
    unsigned short* __restrict__ Kb, unsigned short* __restrict__ Vt) {
  __shared__ float Asm[2][128][16];
  __shared__ unsigned short Bsm[128][32];

  int tid = threadIdx.x;
  int m0g = blockIdx.x * 128;
  int z = m0g >> 13;
  int m0 = m0g & 8191;
  int n0 = blockIdx.y * 128;
  const float* X = (z == 0) ? Xq : ((z == 1) ? Xk : Xv);
  const float* bias = (z == 0) ? bq : ((z == 1) ? bk : bv);
  const unsigned short* Wz = Wt + z * 262144;

  int w = tid >> 6, lane = tid & 63;
  int wm = w >> 1, wn = w & 1;
  int mrow = lane & 15, quad = lane >> 4;

  int srow = tid >> 2, schk = tid & 3;
  const float* gA = X + (m0 + srow) * 512 + schk * 4;
  const unsigned short* gB = Wz + (n0 + srow) * 512 + schk * 8;
  char* lA = (char*)&Asm[0][0][0] + tid * 16;
  char* lB = (char*)&Bsm[0][0] + tid * 16;

  const float* rA = &Asm[quad >> 1][0][(quad & 1) * 8];
  const unsigned short* rB = &Bsm[0][quad * 8];

  f32x4 zero = {0.f, 0.f, 0.f, 0.f};
  f32x4 acc[4][4];
#pragma unroll
  for (int i = 0; i < 4; ++i)
#pragma unroll
    for (int j = 0; j < 4; ++j) acc[i][j] = zero;

  for (int kc = 0; kc < 16; ++kc) {
    int ko = kc * 32;
    g2l16(gA + ko, lA);
    g2l16(gA + ko + 64 * 512, lA + 4096);
    g2l16(gA + ko + 16, lA + 8192);
    g2l16(gA + ko + 16 + 64 * 512, lA + 12288);
    g2l16(gB + ko, lB);
    g2l16(gB + ko + 64 * 512, lB + 4096);
    __syncthreads();

    bf16x8 af[4], bfr[4];
#pragma unroll
    for (int mt = 0; mt < 4; ++mt) {
      const float* pa = rA + (wm * 64 + mt * 16 + mrow) * 16;
      f32x4 lo = *(const f32x4*)pa;
      f32x4 hi = *(const f32x4*)(pa + 4);
      bf16x8 t;
      t[0] = (__bf16)lo[0]; t[1] = (__bf16)lo[1];
      t[2] = (__bf16)lo[2]; t[3] = (__bf16)lo[3];
      t[4] = (__bf16)hi[0]; t[5] = (__bf16)hi[1];
      t[6] = (__bf16)hi[2]; t[7] = (__bf16)hi[3];
      af[mt] = t;
    }
#pragma unroll
    for (int nt = 0; nt < 4; ++nt)
      bfr[nt] = ld_bf8(rB + (wn * 64 + nt * 16 + mrow) * 32);
#pragma unroll
    for (int mt = 0; mt < 4; ++mt)
#pragma unroll
      for (int nt = 0; nt < 4; ++nt)
        acc[mt][nt] = mfma16(af[mt], bfr[nt], acc[mt][nt]);
    __syncthreads();
  }

  if (z < 2) {
    unsigned short* dst = (z == 0) ? Qb : Kb;
    float sc = (z == 0) ? QSCALE : 1.0f;
#pragma unroll
    for (int nt = 0; nt < 4; ++nt) {
      int n = n0 + wn * 64 + nt * 16 + mrow;
      float bv_ = bias[n];
#pragma unroll
      for (int mt = 0; mt < 4; ++mt) {
        int m = m0 + wm * 64 + mt * 16 + quad * 4;
#pragma unroll
        for (int r = 0; r < 4; ++r) {
          float v = fmaxf(acc[mt][nt][r] + bv_, 0.f) * sc;
          dst[(m + r) * 512 + n] = f2bf(v);
        }
      }
    }
  } else {
#pragma unroll
    for (int nt = 0; nt < 4; ++nt) {
      int n = n0 + wn * 64 + nt * 16 + mrow;
      int hh = n >> 6, jj = n & 63;
      float bv_ = bias[n];
#pragma unroll
      for (int mt = 0; mt < 4; ++mt) {
        int grow = m0 + wm * 64 + mt * 16 + quad * 4;
        int bb = grow >> 11, tl = grow & 2047;
        float p0 = fmaxf(acc[mt][nt][0] + bv_, 0.f);
        float p1 = fmaxf(acc[mt][nt][1] + bv_, 0.f);
        float p2 = fmaxf(acc[mt][nt][2] + bv_, 0.f);
        float p3 = fmaxf(acc[mt][nt][3] + bv_, 0.f);
        *(uint2*)(Vt + ((hh * 4 + bb) * 64 + jj) * 2048 + tl) =
            make_uint2(pk2(p0, p1), pk2(p2, p3));
      }
    }
  }
}

// ---------------------------------------------------------------------------
// Kernel 4: attention, key-split across waves, LDS-free main loop.
// Wave w owns keys {128-chunk + w*32 .. +31}; all 64 queries.
// S^T = K*Q^T (C: col=q=lane&15, row=key=quad*4+r). PV uses the k-permutation
// k_phys(quad,j) = 4q+j / 16+4q+(j-4), which makes each lane's P B-fragment
// exactly its own 8 post-exp values (register repack, no cross-lane traffic);
// V A-fragments load two uint2 runs to match. l via ones-A MFMA.
// ---------------------------------------------------------------------------
__global__ __launch_bounds__(256) void attn_kernel(
    const unsigned short* __restrict__ Qb, const unsigned short* __restrict__ Kb,
    const unsigned short* __restrict__ Vt, const float* __restrict__ qmask,
    const float* __restrict__ kmask, const float* __restrict__ queries,
    float* __restrict__ out) {
  __shared__ float Obuf[64 * 68];
  __shared__ float lbuf[4][64];

  int hb = blockIdx.x;
  int qt = blockIdx.y;
  int h = hb >> 2, b = hb & 3;
  int q0 = qt * 64;
  int tid = threadIdx.x;
  int w = tid >> 6, lane = tid & 63;
  int mrow = lane & 15, quad = lane >> 4;

  // Q B-frags [n=q qn*16+mrow][k=dh quad*8], shared by all waves
  bf16x8 qf[4][2];
  {
    const unsigned short* qp = Qb + (b * 2048 + q0 + mrow) * 512 + h * 64 + quad * 8;
#pragma unroll
    for (int qn = 0; qn < 4; ++qn) {
      qf[qn][0] = ld_bf8(qp + qn * 8192);
      qf[qn][1] = ld_bf8(qp + qn * 8192 + 32);
    }
  }

  f32x4 zero = {0.f, 0.f, 0.f, 0.f};
  f32x4 oacc[4][4];
#pragma unroll
  for (int i = 0; i < 4; ++i)
#pragma unroll
    for (int j = 0; j < 4; ++j) oacc[i][j] = zero;
  f32x4 lacc[4];
#pragma unroll
  for (int i = 0; i < 4; ++i) lacc[i] = zero;

  bf16x8 ones;
#pragma unroll
  for (int i = 0; i < 8; ++i) ones[i] = (__bf16)1.0f;

  const unsigned short* kpB = Kb + (b * 2048 + w * 32 + mrow) * 512 + h * 64 + quad * 8;
  const unsigned short* vpB = Vt + (hb * 64 + mrow) * 2048 + w * 32 + quad * 4;
  const float* kmB = kmask + b * 2048 + w * 32 + quad * 4;

  // K A-frags [m=key mt*16+mrow][k=dh quad*8], prefetched one iter ahead
  bf16x8 kf[2][2];
#pragma unroll
  for (int mt = 0; mt < 2; ++mt) {
    kf[mt][0] = ld_bf8(kpB + mt * 8192);
    kf[mt][1] = ld_bf8(kpB + mt * 8192 + 32);
  }

  for (int it = 0; it < 16; ++it) {
    int kb = it << 7;
    // --- QK^T
    f32x4 sacc[2][4];
#pragma unroll
    for (int mt = 0; mt < 2; ++mt)
#pragma unroll
      for (int qn = 0; qn < 4; ++qn) {
        f32x4 s = mfma16(kf[mt][0], qf[qn][0], zero);
        sacc[mt][qn] = mfma16(kf[mt][1], qf[qn][1], s);
      }
    // --- prefetch next K (wraps; last result unused)
    int nkb = ((it + 1) & 15) << 7;
    bf16x8 nkf[2][2];
#pragma unroll
    for (int mt = 0; mt < 2; ++mt) {
      nkf[mt][0] = ld_bf8(kpB + nkb * 512 + mt * 8192);
      nkf[mt][1] = ld_bf8(kpB + nkb * 512 + mt * 8192 + 32);
    }
    // --- V A-frags in the k_phys permutation: two uint2 runs per dt
    bf16x8 vf[4];
#pragma unroll
    for (int dt = 0; dt < 4; ++dt) {
      const unsigned short* vp = vpB + dt * 32768 + kb;
      uint2 lo = *(const uint2*)vp;
      uint2 hi = *(const uint2*)(vp + 16);
      vf[dt] = __builtin_bit_cast(bf16x8, make_uint4(lo.x, lo.y, hi.x, hi.y));
    }
    // --- key mask (keys quad*4+r of each mt half)
    f32x4 km0 = *(const f32x4*)(kmB + kb);
    f32x4 km1 = *(const f32x4*)(kmB + kb + 16);
    // --- per qn: exp, pack -> P frag (register-local), l-MFMA, PV
#pragma unroll
    for (int qn = 0; qn < 4; ++qn) {
      f32x4 p0, p1;
#pragma unroll
      for (int r = 0; r < 4; ++r) {
        p0[r] = EXP2F(sacc[0][qn][r]) * km0[r];
        p1[r] = EXP2F(sacc[1][qn][r]) * km1[r];
      }
      bf16x8 pf = __builtin_bit_cast(
          bf16x8, make_uint4(pk2(p0[0], p0[1]), pk2(p0[2], p0[3]),
                             pk2(p1[0], p1[1]), pk2(p1[2], p1[3])));
      lacc[qn] = mfma16(ones, pf, lacc[qn]);
#pragma unroll
      for (int dt = 0; dt < 4; ++dt)
        oacc[dt][qn] = mfma16(vf[dt], pf, oacc[dt][qn]);
    }
#pragma unroll
    for (int mt = 0; mt < 2; ++mt) {
      kf[mt][0] = nkf[mt][0];
      kf[mt][1] = nkf[mt][1];
    }
  }

  // --- epilogue: publish per-wave l (all quads hold identical copies)
  if (quad == 0) {
#pragma unroll
    for (int qn = 0; qn < 4; ++qn) lbuf[w][qn * 16 + mrow] = lacc[qn][0];
  }
  __syncthreads();

  // --- sum partial O across waves into Obuf [64 q][68]
  for (int ph = 0; ph < 4; ++ph) {
    if (w == ph) {
#pragma unroll
      for (int dt = 0; dt < 4; ++dt)
#pragma unroll
        for (int qn = 0; qn < 4; ++qn) {
          float* dst = Obuf + (qn * 16 + mrow) * 68 + dt * 16 + quad * 4;
          f32x4 v = oacc[dt][qn];
          if (ph) {
            v[0] += dst[0]; v[1] += dst[1]; v[2] += dst[2]; v[3] += dst[3];
          }
          dst[0] = v[0]; dst[1] = v[1]; dst[2] = v[2]; dst[3] = v[3];
        }
    }
    __syncthreads();
  }

  // --- scale by qmask/l, add residual, store fp32 (coalesced float4)
#pragma unroll
  for (int i = 0; i < 4; ++i) {
    int qr = w * 16 + i * 4 + quad;
    float l = lbuf[0][qr] + lbuf[1][qr] + lbuf[2][qr] + lbuf[3][qr];
    int qg = b * 2048 + q0 + qr;
    float inv = qmask[qg] / l;
    const float* ob = Obuf + qr * 68 + mrow * 4;
    const float4 res = *(const float4*)(queries + qg * 512 + h * 64 + mrow * 4);
    float4 r;
    r.x = ob[0] * inv + res.x;
    r.y = ob[1] * inv + res.y;
    r.z = ob[2] * inv + res.z;
    r.w = ob[3] * inv + res.w;
    *(float4*)(out + qg * 512 + h * 64 + mrow * 4) = r;
  }
}

// ---------------------------------------------------------------------------
// Kernel 5: LayerNorm (unbiased std, eps added to std), in-place on d_out.
// ---------------------------------------------------------------------------
__global__ __launch_bounds__(256) void ln_kernel(float* __restrict__ out,
                                                 const float* __restrict__ gamma,
                                                 const float* __restrict__ beta) {
  int row = blockIdx.x * 4 + (threadIdx.x >> 6);
  int lane = threadIdx.x & 63;
  float* p = out + row * 512;
  float4 v1 = ((const float4*)p)[lane];
  float4 v2 = ((const float4*)p)[64 + lane];
  float s = v1.x + v1.y + v1.z + v1.w + v2.x + v2.y + v2.z + v2.w;
  float sq = v1.x * v1.x + v1.y * v1.y + v1.z * v1.z + v1.w * v1.w +
             v2.x * v2.x + v2.y * v2.y + v2.z * v2.z + v2.w * v2.w;
#pragma unroll
  for (int off = 32; off > 0; off >>= 1) {
    s += __shfl_xor(s, off);
    sq += __shfl_xor(sq, off);
  }
  float mean = s * (1.f / 512.f);
  float var = fmaxf((sq - 512.f * mean * mean) * (1.f / 511.f), 0.f);
  float inv = 1.f / (sqrtf(var) + 1e-8f);
  float4 g1 = ((const float4*)gamma)[lane];
  float4 g2 = ((const float4*)gamma)[64 + lane];
  float4 b1 = ((const float4*)beta)[lane];
  float4 b2 = ((const float4*)beta)[64 + lane];
  v1.x = g1.x * (v1.x - mean) * inv + b1.x;
  v1.y = g1.y * (v1.y - mean) * inv + b1.y;
  v1.z = g1.z * (v1.z - mean) * inv + b1.z;
  v1.w = g1.w * (v1.w - mean) * inv + b1.w;
  v2.x = g2.x * (v2.x - mean) * inv + b2.x;
  v2.y = g2.y * (v2.y - mean) * inv + b2.y;
  v2.z = g2.z * (v2.z - mean) * inv + b2.z;
  v2.w = g2.w * (v2.w - mean) * inv + b2.w;
  ((float4*)p)[lane] = v1;
  ((float4*)p)[64 + lane] = v2;
}

// ---------------------------------------------------------------------------
extern "C" void kernel_launch(void* const* d_in, const int* in_sizes, int n_in,
                              void* d_out, int out_size, void* d_ws, size_t ws_size,
                              hipStream_t stream) {
  (void)in_sizes; (void)n_in; (void)out_size; (void)ws_size;
  const float* queries = (const float*)d_in[0];
  const float* keys    = (const float*)d_in[1];
  const float* values  = (const float*)d_in[2];
  const float* Wq = (const float*)d_in[3];
  const float* bq = (const float*)d_in[4];
  const float* Wk = (const float*)d_in[5];
  const float* bk = (const float*)d_in[6];
  const float* Wv = (const float*)d_in[7];
  const float* bv = (const float*)d_in[8];
  const float* gamma = (const float*)d_in[9];
  const float* beta  = (const float*)d_in[10];
  float* out = (float*)d_out;

  char* ws = (char*)d_ws;
  unsigned short* Qb = (unsigned short*)(ws);                    // 8 MB
  unsigned short* Kb = (unsigned short*)(ws + 8 * 1024 * 1024);  // 8 MB
  unsigned short* Vt = (unsigned short*)(ws + 16 * 1024 * 1024); // 8 MB  [32][64][2048]
  unsigned short* Wt = (unsigned short*)(ws + 24 * 1024 * 1024); // 1.5 MB
  float* qmask = (float*)(ws + 24 * 1024 * 1024 + 3 * 512 * 512 * 2);
  float* kmask = qmask + 8192;

  wt_kernel<<<384, 256, 0, stream>>>(Wq, Wk, Wv, Wt);
  mask_kernel<<<4096, 256, 0, stream>>>(queries, keys, qmask, kmask);
  proj_kernel<<<dim3(192, 4), 256, 0, stream>>>(queries, keys, values, bq, bk, bv,
                                                Wt, Qb, Kb, Vt);
  attn_kernel<<<dim3(32, 32), 256, 0, stream>>>(Qb, Kb, Vt, qmask, kmask, queries, out);
  ln_kernel<<<2048, 256, 0, stream>>>(out, gamma, beta);
}

// Round 5
// 218.021 us; speedup vs baseline: 1.0948x; 1.0948x over previous
//
#include <hip/hip_runtime.h>

// R5: attn key-loop software-pipelined with TWO register sets (unroll x2):
// K, V, and km for chunk i+1 are all in flight while chunk i computes --
// one overlapped latency round per iteration (R4 exposed V+km latency
// in-iteration; ~4000 cyc/wave-iter measured vs ~250 compute).
// Vt intra-32-key order permuted at proj-write time so each V A-fragment is
// a single 16-B load matching the P register repack. launch_bounds(256,2).

typedef __attribute__((ext_vector_type(8))) __bf16 bf16x8;
typedef __attribute__((ext_vector_type(4))) float f32x4;

#if __has_builtin(__builtin_amdgcn_exp2f)
#define EXP2F __builtin_amdgcn_exp2f
#else
#define EXP2F exp2f
#endif

#define QSCALE (0.125f * 1.4426950408889634f)  // fold /sqrt(64) and ln->log2

__device__ __forceinline__ unsigned short f2bf(float f) {
  return __builtin_bit_cast(unsigned short, (__bf16)f);
}
__device__ __forceinline__ unsigned pk2(float a, float b) {
  return (unsigned)f2bf(a) | ((unsigned)f2bf(b) << 16);
}
__device__ __forceinline__ f32x4 mfma16(bf16x8 a, bf16x8 b, f32x4 c) {
  return __builtin_amdgcn_mfma_f32_16x16x32_bf16(a, b, c, 0, 0, 0);
}
__device__ __forceinline__ bf16x8 ld_bf8(const unsigned short* p) {
  return *(const bf16x8*)p;
}
// async global->LDS, 16 B per lane; LDS dst must be wave-uniform base + lane*16
__device__ __forceinline__ void g2l16(const void* g, void* l) {
  __builtin_amdgcn_global_load_lds(
      (const __attribute__((address_space(1))) void*)g,
      (__attribute__((address_space(3))) void*)l, 16, 0, 0);
}

// ---------------------------------------------------------------------------
// Kernel 1: transpose + convert the three 512x512 weight matrices to bf16,
// layout Wt[z][n][k] (n-major) so MFMA B-fragments read contiguous k.
// ---------------------------------------------------------------------------
__global__ __launch_bounds__(256) void wt_kernel(const float* __restrict__ Wq,
                                                 const float* __restrict__ Wk,
                                                 const float* __restrict__ Wv,
                                                 unsigned short* __restrict__ Wt) {
  int idx = blockIdx.x * 256 + threadIdx.x;
  int o = idx * 8;
  int z = o >> 18;
  int rem = o & 262143;
  int n = rem >> 9;
  int k0 = rem & 511;
  const float* W = (z == 0) ? Wq : ((z == 1) ? Wk : Wv);
  unsigned int w[4];
#pragma unroll
  for (int i = 0; i < 4; ++i) {
    unsigned short lo = f2bf(W[(k0 + 2 * i) * 512 + n]);
    unsigned short hi = f2bf(W[(k0 + 2 * i + 1) * 512 + n]);
    w[i] = (unsigned)lo | ((unsigned)hi << 16);
  }
  *(uint4*)(Wt + o) = make_uint4(w[0], w[1], w[2], w[3]);
}

// ---------------------------------------------------------------------------
// Kernel 2: key/query padding masks: sign(|row sum|) of the RAW inputs.
// ---------------------------------------------------------------------------
__global__ __launch_bounds__(256) void mask_kernel(const float* __restrict__ q,
                                                   const float* __restrict__ k,
                                                   float* __restrict__ qmask,
                                                   float* __restrict__ kmask) {
  int w = blockIdx.x * 4 + (threadIdx.x >> 6);
  int lane = threadIdx.x & 63;
  const float* src = (w < 8192) ? q : k;
  int row = w & 8191;
  const float4* p = (const float4*)(src + row * 512);
  float4 v1 = p[lane];
  float4 v2 = p[64 + lane];
  float s = v1.x + v1.y + v1.z + v1.w + v2.x + v2.y + v2.z + v2.w;
#pragma unroll
  for (int off = 32; off > 0; off >>= 1) s += __shfl_xor(s, off);
  if (lane == 0) {
    float m = (s == 0.0f) ? 0.0f : 1.0f;
    if (w < 8192) qmask[row] = m; else kmask[row] = m;
  }
}

// ---------------------------------------------------------------------------
// Kernel 3: QKV projection as m97-style GEMM (R3 structure). V epilogue now
// stores in the PERMUTED intra-32-key order: within each 32-t group,
// pos = quad*8 + (mt&1)*4 + r, so attn's V A-frag is one contiguous 16-B run.
// ---------------------------------------------------------------------------
__global__ __launch_bounds__(256, 3) void proj_kernel(
    const float* __restrict__ Xq, const float* __restrict__ Xk,
    const float* __restrict__ Xv, const float* __restrict__ bq,
    const float* __restrict__ bk, const float* __restrict__ bv,
    const unsigned short* __restrict__ Wt, unsigned short* __restrict__ Qb,
    unsigned short* __restrict__ Kb, unsigned short* __restrict__ Vt) {
  __shared__ float Asm[2][128][16];
  __shared__ unsigned short Bsm[128][32];

  int tid = threadIdx.x;
  int m0g = blockIdx.x * 128;
  int z = m0g >> 13;
  int m0 = m0g & 8191;
  int n0 = blockIdx.y * 128;
  const float* X = (z == 0) ? Xq : ((z == 1) ? Xk : Xv);
  const float* bias = (z == 0) ? bq : ((z == 1) ? bk : bv);
  const unsigned short* Wz = Wt + z * 262144;

  int w = tid >> 6, lane = tid & 63;
  int wm = w >> 1, wn = w & 1;
  int mrow = lane & 15, quad = lane >> 4;

  int srow = tid >> 2, schk = tid & 3;
  const float* gA = X + (m0 + srow) * 512 + schk * 4;
  const unsigned short* gB = Wz + (n0 + srow) * 512 + schk * 8;
  char* lA = (char*)&Asm[0][0][0] + tid * 16;
  char* lB = (char*)&Bsm[0][0] + tid * 16;

  const float* rA = &Asm[quad >> 1][0][(quad & 1) * 8];
  const unsigned short* rB = &Bsm[0][quad * 8];

  f32x4 zero = {0.f, 0.f, 0.f, 0.f};
  f32x4 acc[4][4];
#pragma unroll
  for (int i = 0; i < 4; ++i)
#pragma unroll
    for (int j = 0; j < 4; ++j) acc[i][j] = zero;

  for (int kc = 0; kc < 16; ++kc) {
    int ko = kc * 32;
    g2l16(gA + ko, lA);
    g2l16(gA + ko + 64 * 512, lA + 4096);
    g2l16(gA + ko + 16, lA + 8192);
    g2l16(gA + ko + 16 + 64 * 512, lA + 12288);
    g2l16(gB + ko, lB);
    g2l16(gB + ko + 64 * 512, lB + 4096);
    __syncthreads();

    bf16x8 af[4], bfr[4];
#pragma unroll
    for (int mt = 0; mt < 4; ++mt) {
      const float* pa = rA + (wm * 64 + mt * 16 + mrow) * 16;
      f32x4 lo = *(const f32x4*)pa;
      f32x4 hi = *(const f32x4*)(pa + 4);
      bf16x8 t;
      t[0] = (__bf16)lo[0]; t[1] = (__bf16)lo[1];
      t[2] = (__bf16)lo[2]; t[3] = (__bf16)lo[3];
      t[4] = (__bf16)hi[0]; t[5] = (__bf16)hi[1];
      t[6] = (__bf16)hi[2]; t[7] = (__bf16)hi[3];
      af[mt] = t;
    }
#pragma unroll
    for (int nt = 0; nt < 4; ++nt)
      bfr[nt] = ld_bf8(rB + (wn * 64 + nt * 16 + mrow) * 32);
#pragma unroll
    for (int mt = 0; mt < 4; ++mt)
#pragma unroll
      for (int nt = 0; nt < 4; ++nt)
        acc[mt][nt] = mfma16(af[mt], bfr[nt], acc[mt][nt]);
    __syncthreads();
  }

  if (z < 2) {
    unsigned short* dst = (z == 0) ? Qb : Kb;
    float sc = (z == 0) ? QSCALE : 1.0f;
#pragma unroll
    for (int nt = 0; nt < 4; ++nt) {
      int n = n0 + wn * 64 + nt * 16 + mrow;
      float bv_ = bias[n];
#pragma unroll
      for (int mt = 0; mt < 4; ++mt) {
        int m = m0 + wm * 64 + mt * 16 + quad * 4;
#pragma unroll
        for (int r = 0; r < 4; ++r) {
          float v = fmaxf(acc[mt][nt][r] + bv_, 0.f) * sc;
          dst[(m + r) * 512 + n] = f2bf(v);
        }
      }
    }
  } else {
    // V: permuted-transposed store. grow's t32-group (mt&1)*16 + quad*4 + r
    // lands at pos = quad*8 + (mt&1)*4 + r within its 32-t group.
#pragma unroll
    for (int nt = 0; nt < 4; ++nt) {
      int n = n0 + wn * 64 + nt * 16 + mrow;
      int hh = n >> 6, jj = n & 63;
      float bv_ = bias[n];
#pragma unroll
      for (int mt = 0; mt < 4; ++mt) {
        int grow = m0 + wm * 64 + mt * 16 + quad * 4;
        int bb = grow >> 11, tl = grow & 2047;
        int pos = (tl & ~31) + quad * 8 + (mt & 1) * 4;
        float p0 = fmaxf(acc[mt][nt][0] + bv_, 0.f);
        float p1 = fmaxf(acc[mt][nt][1] + bv_, 0.f);
        float p2 = fmaxf(acc[mt][nt][2] + bv_, 0.f);
        float p3 = fmaxf(acc[mt][nt][3] + bv_, 0.f);
        *(uint2*)(Vt + ((hh * 4 + bb) * 64 + jj) * 2048 + pos) =
            make_uint2(pk2(p0, p1), pk2(p2, p3));
      }
    }
  }
}

// ---------------------------------------------------------------------------
// Kernel 4: attention, key-split across waves, LDS-free, double-buffered
// register pipeline (unroll x2, sets a/b). Wave w owns keys
// {128-chunk + w*32..+31}, all 64 queries. PV k-order = register repack
// (pf IS the lane's own post-exp values); Vt permuted to match.
// ---------------------------------------------------------------------------
#define LOADSET(P, KB)                              \
  P##k00 = ld_bf8(kpB + (KB) * 512);                \
  P##k01 = ld_bf8(kpB + (KB) * 512 + 32);           \
  P##k10 = ld_bf8(kpB + (KB) * 512 + 8192);         \
  P##k11 = ld_bf8(kpB + (KB) * 512 + 8192 + 32);    \
  P##v0 = ld_bf8(vpB + (KB));                       \
  P##v1 = ld_bf8(vpB + (KB) + 32768);               \
  P##v2 = ld_bf8(vpB + (KB) + 65536);               \
  P##v3 = ld_bf8(vpB + (KB) + 98304);               \
  P##km0 = *(const f32x4*)(kmB + (KB));             \
  P##km1 = *(const f32x4*)(kmB + (KB) + 16);

#define COMPUTESET(P)                                                   \
  {                                                                     \
    f32x4 sacc0[4], sacc1[4];                                           \
    _Pragma("unroll") for (int qn = 0; qn < 4; ++qn) {                  \
      f32x4 s0 = mfma16(P##k00, qf[qn][0], zero);                       \
      sacc0[qn] = mfma16(P##k01, qf[qn][1], s0);                        \
      f32x4 s1 = mfma16(P##k10, qf[qn][0], zero);                       \
      sacc1[qn] = mfma16(P##k11, qf[qn][1], s1);                        \
    }                                                                   \
    _Pragma("unroll") for (int qn = 0; qn < 4; ++qn) {                  \
      f32x4 p0, p1;                                                     \
      _Pragma("unroll") for (int r = 0; r < 4; ++r) {                   \
        p0[r] = EXP2F(sacc0[qn][r]) * P##km0[r];                        \
        p1[r] = EXP2F(sacc1[qn][r]) * P##km1[r];                        \
      }                                                                 \
      bf16x8 pf = __builtin_bit_cast(                                   \
          bf16x8, make_uint4(pk2(p0[0], p0[1]), pk2(p0[2], p0[3]),      \
                             pk2(p1[0], p1[1]), pk2(p1[2], p1[3])));    \
      lacc[qn] = mfma16(ones, pf, lacc[qn]);                            \
      oacc[0][qn] = mfma16(P##v0, pf, oacc[0][qn]);                     \
      oacc[1][qn] = mfma16(P##v1, pf, oacc[1][qn]);                     \
      oacc[2][qn] = mfma16(P##v2, pf, oacc[2][qn]);                     \
      oacc[3][qn] = mfma16(P##v3, pf, oacc[3][qn]);                     \
    }                                                                   \
  }

__global__ __launch_bounds__(256, 2) void attn_kernel(
    const unsigned short* __restrict__ Qb, const unsigned short* __restrict__ Kb,
    const unsigned short* __restrict__ Vt, const float* __restrict__ qmask,
    const float* __restrict__ kmask, const float* __restrict__ queries,
    float* __restrict__ out) {
  __shared__ float Obuf[64 * 68];
  __shared__ float lbuf[4][64];

  int hb = blockIdx.x;
  int qt = blockIdx.y;
  int h = hb >> 2, b = hb & 3;
  int q0 = qt * 64;
  int tid = threadIdx.x;
  int w = tid >> 6, lane = tid & 63;
  int mrow = lane & 15, quad = lane >> 4;

  // Q B-frags [n=q qn*16+mrow][k=dh quad*8], shared by all waves
  bf16x8 qf[4][2];
  {
    const unsigned short* qp = Qb + (b * 2048 + q0 + mrow) * 512 + h * 64 + quad * 8;
#pragma unroll
    for (int qn = 0; qn < 4; ++qn) {
      qf[qn][0] = ld_bf8(qp + qn * 8192);
      qf[qn][1] = ld_bf8(qp + qn * 8192 + 32);
    }
  }

  f32x4 zero = {0.f, 0.f, 0.f, 0.f};
  f32x4 oacc[4][4];
#pragma unroll
  for (int i = 0; i < 4; ++i)
#pragma unroll
    for (int j = 0; j < 4; ++j) oacc[i][j] = zero;
  f32x4 lacc[4];
#pragma unroll
  for (int i = 0; i < 4; ++i) lacc[i] = zero;

  bf16x8 ones;
#pragma unroll
  for (int i = 0; i < 8; ++i) ones[i] = (__bf16)1.0f;

  const unsigned short* kpB = Kb + (b * 2048 + w * 32 + mrow) * 512 + h * 64 + quad * 8;
  const unsigned short* vpB = Vt + (hb * 64 + mrow) * 2048 + w * 32 + quad * 8;
  const float* kmB = kmask + b * 2048 + w * 32 + quad * 4;

  bf16x8 ak00, ak01, ak10, ak11, av0, av1, av2, av3;
  bf16x8 bk00, bk01, bk10, bk11, bv0, bv1, bv2, bv3;
  f32x4 akm0, akm1, bkm0, bkm1;

  LOADSET(a, 0)
  for (int it = 0; it < 16; it += 2) {
    LOADSET(b, (it + 1) * 128)
    COMPUTESET(a)
    LOADSET(a, ((it + 2) & 15) * 128)  // wraps to 0 on last pass (unused)
    COMPUTESET(b)
  }

  // --- epilogue: publish per-wave l (all quads hold identical copies)
  if (quad == 0) {
#pragma unroll
    for (int qn = 0; qn < 4; ++qn) lbuf[w][qn * 16 + mrow] = lacc[qn][0];
  }
  __syncthreads();

  // --- sum partial O across waves into Obuf [64 q][68]
  for (int ph = 0; ph < 4; ++ph) {
    if (w == ph) {
#pragma unroll
      for (int dt = 0; dt < 4; ++dt)
#pragma unroll
        for (int qn = 0; qn < 4; ++qn) {
          float* dst = Obuf + (qn * 16 + mrow) * 68 + dt * 16 + quad * 4;
          f32x4 v = oacc[dt][qn];
          if (ph) {
            v[0] += dst[0]; v[1] += dst[1]; v[2] += dst[2]; v[3] += dst[3];
          }
          dst[0] = v[0]; dst[1] = v[1]; dst[2] = v[2]; dst[3] = v[3];
        }
    }
    __syncthreads();
  }

  // --- scale by qmask/l, add residual, store fp32 (coalesced float4)
#pragma unroll
  for (int i = 0; i < 4; ++i) {
    int qr = w * 16 + i * 4 + quad;
    float l = lbuf[0][qr] + lbuf[1][qr] + lbuf[2][qr] + lbuf[3][qr];
    int qg = b * 2048 + q0 + qr;
    float inv = qmask[qg] / l;
    const float* ob = Obuf + qr * 68 + mrow * 4;
    const float4 res = *(const float4*)(queries + qg * 512 + h * 64 + mrow * 4);
    float4 r;
    r.x = ob[0] * inv + res.x;
    r.y = ob[1] * inv + res.y;
    r.z = ob[2] * inv + res.z;
    r.w = ob[3] * inv + res.w;
    *(float4*)(out + qg * 512 + h * 64 + mrow * 4) = r;
  }
}

// ---------------------------------------------------------------------------
// Kernel 5: LayerNorm (unbiased std, eps added to std), in-place on d_out.
// ---------------------------------------------------------------------------
__global__ __launch_bounds__(256) void ln_kernel(float* __restrict__ out,
                                                 const float* __restrict__ gamma,
                                                 const float* __restrict__ beta) {
  int row = blockIdx.x * 4 + (threadIdx.x >> 6);
  int lane = threadIdx.x & 63;
  float* p = out + row * 512;
  float4 v1 = ((const float4*)p)[lane];
  float4 v2 = ((const float4*)p)[64 + lane];
  float s = v1.x + v1.y + v1.z + v1.w + v2.x + v2.y + v2.z + v2.w;
  float sq = v1.x * v1.x + v1.y * v1.y + v1.z * v1.z + v1.w * v1.w +
             v2.x * v2.x + v2.y * v2.y + v2.z * v2.z + v2.w * v2.w;
#pragma unroll
  for (int off = 32; off > 0; off >>= 1) {
    s += __shfl_xor(s, off);
    sq += __shfl_xor(sq, off);
  }
  float mean = s * (1.f / 512.f);
  float var = fmaxf((sq - 512.f * mean * mean) * (1.f / 511.f), 0.f);
  float inv = 1.f / (sqrtf(var) + 1e-8f);
  float4 g1 = ((const float4*)gamma)[lane];
  float4 g2 = ((const float4*)gamma)[64 + lane];
  float4 b1 = ((const float4*)beta)[lane];
  float4 b2 = ((const float4*)beta)[64 + lane];
  v1.x = g1.x * (v1.x - mean) * inv + b1.x;
  v1.y = g1.y * (v1.y - mean) * inv + b1.y;
  v1.z = g1.z * (v1.z - mean) * inv + b1.z;
  v1.w = g1.w * (v1.w - mean) * inv + b1.w;
  v2.x = g2.x * (v2.x - mean) * inv + b2.x;
  v2.y = g2.y * (v2.y - mean) * inv + b2.y;
  v2.z = g2.z * (v2.z - mean) * inv + b2.z;
  v2.w = g2.w * (v2.w - mean) * inv + b2.w;
  ((float4*)p)[lane] = v1;
  ((float4*)p)[64 + lane] = v2;
}

// ---------------------------------------------------------------------------
extern "C" void kernel_launch(void* const* d_in, const int* in_sizes, int n_in,
                              void* d_out, int out_size, void* d_ws, size_t ws_size,
                              hipStream_t stream) {
  (void)in_sizes; (void)n_in; (void)out_size; (void)ws_size;
  const float* queries = (const float*)d_in[0];
  const float* keys    = (const float*)d_in[1];
  const float* values  = (const float*)d_in[2];
  const float* Wq = (const float*)d_in[3];
  const float* bq = (const float*)d_in[4];
  const float* Wk = (const float*)d_in[5];
  const float* bk = (const float*)d_in[6];
  const float* Wv = (const float*)d_in[7];
  const float* bv = (const float*)d_in[8];
  const float* gamma = (const float*)d_in[9];
  const float* beta  = (const float*)d_in[10];
  float* out = (float*)d_out;

  char* ws = (char*)d_ws;
  unsigned short* Qb = (unsigned short*)(ws);                    // 8 MB
  unsigned short* Kb = (unsigned short*)(ws + 8 * 1024 * 1024);  // 8 MB
  unsigned short* Vt = (unsigned short*)(ws + 16 * 1024 * 1024); // 8 MB  [32][64][2048]
  unsigned short* Wt = (unsigned short*)(ws + 24 * 1024 * 1024); // 1.5 MB
  float* qmask = (float*)(ws + 24 * 1024 * 1024 + 3 * 512 * 512 * 2);
  float* kmask = qmask + 8192;

  wt_kernel<<<384, 256, 0, stream>>>(Wq, Wk, Wv, Wt);
  mask_kernel<<<4096, 256, 0, stream>>>(queries, keys, qmask, kmask);
  proj_kernel<<<dim3(192, 4), 256, 0, stream>>>(queries, keys, values, bq, bk, bv,
                                                Wt, Qb, Kb, Vt);
  attn_kernel<<<dim3(32, 32), 256, 0, stream>>>(Qb, Kb, Vt, qmask, kmask, queries, out);
  ln_kernel<<<2048, 256, 0, stream>>>(out, gamma, beta);
}

// Round 6
// 201.177 us; speedup vs baseline: 1.1865x; 1.0837x over previous
//
#include <hip/hip_runtime.h>

// R6: attn restructured to query-split waves + block-shared K/V staged in LDS.
// Block = (hb, 128 q): 4 waves x 32 q; 32 chunks of 64 keys, K/V staged once
// per block (4x less L2 traffic than R5) via global_load_lds with XOR-swizzled
// lane->global mapping (fragment ds_read_b128 then hits all 32 banks
// uniformly). PV computed as O = P*V^T with P as A-operand (same register
// repack as R5; A/B share the lane mapping), so C-layout has col=dh ->
// coalesced direct stores, no cross-wave O reduction. Persistent regs/wave
// ~56 (oacc 32, qf 16, lvec 8). proj/wt/mask/ln unchanged from R5.

typedef __attribute__((ext_vector_type(8))) __bf16 bf16x8;
typedef __attribute__((ext_vector_type(4))) float f32x4;

#if __has_builtin(__builtin_amdgcn_exp2f)
#define EXP2F __builtin_amdgcn_exp2f
#else
#define EXP2F exp2f
#endif

#define QSCALE (0.125f * 1.4426950408889634f)  // fold /sqrt(64) and ln->log2

__device__ __forceinline__ unsigned short f2bf(float f) {
  return __builtin_bit_cast(unsigned short, (__bf16)f);
}
__device__ __forceinline__ unsigned pk2(float a, float b) {
  return (unsigned)f2bf(a) | ((unsigned)f2bf(b) << 16);
}
__device__ __forceinline__ f32x4 mfma16(bf16x8 a, bf16x8 b, f32x4 c) {
  return __builtin_amdgcn_mfma_f32_16x16x32_bf16(a, b, c, 0, 0, 0);
}
__device__ __forceinline__ bf16x8 ld_bf8(const unsigned short* p) {
  return *(const bf16x8*)p;
}
// async global->LDS, 16 B per lane; LDS dst is wave-uniform base + lane*16
__device__ __forceinline__ void g2l16(const void* g, void* l) {
  __builtin_amdgcn_global_load_lds(
      (const __attribute__((address_space(1))) void*)g,
      (__attribute__((address_space(3))) void*)l, 16, 0, 0);
}

// ---------------------------------------------------------------------------
// Kernel 1: transpose + convert the three 512x512 weight matrices to bf16,
// layout Wt[z][n][k] (n-major) so MFMA B-fragments read contiguous k.
// ---------------------------------------------------------------------------
__global__ __launch_bounds__(256) void wt_kernel(const float* __restrict__ Wq,
                                                 const float* __restrict__ Wk,
                                                 const float* __restrict__ Wv,
                                                 unsigned short* __restrict__ Wt) {
  int idx = blockIdx.x * 256 + threadIdx.x;
  int o = idx * 8;
  int z = o >> 18;
  int rem = o & 262143;
  int n = rem >> 9;
  int k0 = rem & 511;
  const float* W = (z == 0) ? Wq : ((z == 1) ? Wk : Wv);
  unsigned int w[4];
#pragma unroll
  for (int i = 0; i < 4; ++i) {
    unsigned short lo = f2bf(W[(k0 + 2 * i) * 512 + n]);
    unsigned short hi = f2bf(W[(k0 + 2 * i + 1) * 512 + n]);
    w[i] = (unsigned)lo | ((unsigned)hi << 16);
  }
  *(uint4*)(Wt + o) = make_uint4(w[0], w[1], w[2], w[3]);
}

// ---------------------------------------------------------------------------
// Kernel 2: key/query padding masks: sign(|row sum|) of the RAW inputs.
// ---------------------------------------------------------------------------
__global__ __launch_bounds__(256) void mask_kernel(const float* __restrict__ q,
                                                   const float* __restrict__ k,
                                                   float* __restrict__ qmask,
                                                   float* __restrict__ kmask) {
  int w = blockIdx.x * 4 + (threadIdx.x >> 6);
  int lane = threadIdx.x & 63;
  const float* src = (w < 8192) ? q : k;
  int row = w & 8191;
  const float4* p = (const float4*)(src + row * 512);
  float4 v1 = p[lane];
  float4 v2 = p[64 + lane];
  float s = v1.x + v1.y + v1.z + v1.w + v2.x + v2.y + v2.z + v2.w;
#pragma unroll
  for (int off = 32; off > 0; off >>= 1) s += __shfl_xor(s, off);
  if (lane == 0) {
    float m = (s == 0.0f) ? 0.0f : 1.0f;
    if (w < 8192) qmask[row] = m; else kmask[row] = m;
  }
}

// ---------------------------------------------------------------------------
// Kernel 3: QKV projection as m97-style GEMM (R3 structure). V stored
// transposed with the permuted intra-32-key order (pos = quad*8+(mt&1)*4+r).
// ---------------------------------------------------------------------------
__global__ __launch_bounds__(256, 3) void proj_kernel(
    const float* __restrict__ Xq, const float* __restrict__ Xk,
    const float* __restrict__ Xv, const float* __restrict__ bq,
    const float* __restrict__ bk, const float* __restrict__ bv,
    const unsigned short* __restrict__ Wt, unsigned short* __restrict__ Qb,
    unsigned short* __restrict__ Kb, unsigned short* __restrict__ Vt) {
  __shared__ float Asm[2][128][16];
  __shared__ unsigned short Bsm[128][32];

  int tid = threadIdx.x;
  int m0g = blockIdx.x * 128;
  int z = m0g >> 13;
  int m0 = m0g & 8191;
  int n0 = blockIdx.y * 128;
  const float* X = (z == 0) ? Xq : ((z == 1) ? Xk : Xv);
  const float* bias = (z == 0) ? bq : ((z == 1) ? bk : bv);
  const unsigned short* Wz = Wt + z * 262144;

  int w = tid >> 6, lane = tid & 63;
  int wm = w >> 1, wn = w & 1;
  int mrow = lane & 15, quad = lane >> 4;

  int srow = tid >> 2, schk = tid & 3;
  const float* gA = X + (m0 + srow) * 512 + schk * 4;
  const unsigned short* gB = Wz + (n0 + srow) * 512 + schk * 8;
  char* lA = (char*)&Asm[0][0][0] + tid * 16;
  char* lB = (char*)&Bsm[0][0] + tid * 16;

  const float* rA = &Asm[quad >> 1][0][(quad & 1) * 8];
  const unsigned short* rB = &Bsm[0][quad * 8];

  f32x4 zero = {0.f, 0.f, 0.f, 0.f};
  f32x4 acc[4][4];
#pragma unroll
  for (int i = 0; i < 4; ++i)
#pragma unroll
    for (int j = 0; j < 4; ++j) acc[i][j] = zero;

  for (int kc = 0; kc < 16; ++kc) {
    int ko = kc * 32;
    g2l16(gA + ko, lA);
    g2l16(gA + ko + 64 * 512, lA + 4096);
    g2l16(gA + ko + 16, lA + 8192);
    g2l16(gA + ko + 16 + 64 * 512, lA + 12288);
    g2l16(gB + ko, lB);
    g2l16(gB + ko + 64 * 512, lB + 4096);
    __syncthreads();

    bf16x8 af[4], bfr[4];
#pragma unroll
    for (int mt = 0; mt < 4; ++mt) {
      const float* pa = rA + (wm * 64 + mt * 16 + mrow) * 16;
      f32x4 lo = *(const f32x4*)pa;
      f32x4 hi = *(const f32x4*)(pa + 4);
      bf16x8 t;
      t[0] = (__bf16)lo[0]; t[1] = (__bf16)lo[1];
      t[2] = (__bf16)lo[2]; t[3] = (__bf16)lo[3];
      t[4] = (__bf16)hi[0]; t[5] = (__bf16)hi[1];
      t[6] = (__bf16)hi[2]; t[7] = (__bf16)hi[3];
      af[mt] = t;
    }
#pragma unroll
    for (int nt = 0; nt < 4; ++nt)
      bfr[nt] = ld_bf8(rB + (wn * 64 + nt * 16 + mrow) * 32);
#pragma unroll
    for (int mt = 0; mt < 4; ++mt)
#pragma unroll
      for (int nt = 0; nt < 4; ++nt)
        acc[mt][nt] = mfma16(af[mt], bfr[nt], acc[mt][nt]);
    __syncthreads();
  }

  if (z < 2) {
    unsigned short* dst = (z == 0) ? Qb : Kb;
    float sc = (z == 0) ? QSCALE : 1.0f;
#pragma unroll
    for (int nt = 0; nt < 4; ++nt) {
      int n = n0 + wn * 64 + nt * 16 + mrow;
      float bv_ = bias[n];
#pragma unroll
      for (int mt = 0; mt < 4; ++mt) {
        int m = m0 + wm * 64 + mt * 16 + quad * 4;
#pragma unroll
        for (int r = 0; r < 4; ++r) {
          float v = fmaxf(acc[mt][nt][r] + bv_, 0.f) * sc;
          dst[(m + r) * 512 + n] = f2bf(v);
        }
      }
    }
  } else {
    // V: permuted-transposed store (pos = quad*8 + (mt&1)*4 + r in 32-t group)
#pragma unroll
    for (int nt = 0; nt < 4; ++nt) {
      int n = n0 + wn * 64 + nt * 16 + mrow;
      int hh = n >> 6, jj = n & 63;
      float bv_ = bias[n];
#pragma unroll
      for (int mt = 0; mt < 4; ++mt) {
        int grow = m0 + wm * 64 + mt * 16 + quad * 4;
        int bb = grow >> 11, tl = grow & 2047;
        int pos = (tl & ~31) + quad * 8 + (mt & 1) * 4;
        float p0 = fmaxf(acc[mt][nt][0] + bv_, 0.f);
        float p1 = fmaxf(acc[mt][nt][1] + bv_, 0.f);
        float p2 = fmaxf(acc[mt][nt][2] + bv_, 0.f);
        float p3 = fmaxf(acc[mt][nt][3] + bv_, 0.f);
        *(uint2*)(Vt + ((hh * 4 + bb) * 64 + jj) * 2048 + pos) =
            make_uint2(pk2(p0, p1), pk2(p2, p3));
      }
    }
  }
}

// ---------------------------------------------------------------------------
// Kernel 4: attention, query-split waves + LDS-shared K/V.
// Grid (hb=32, qt=16). Block: 4 waves, wave w owns queries q0+w*32..+31.
// Loop: 32 chunks of 64 keys; K chunk [64 key][64 dh] and V chunk
// [64 dh][64 key-permuted] staged via g2l16 with XOR-swizzle (slot s of row r
// holds chunk s^(r&7)). QK: S^T = K*Q^T (A=K from LDS, B=Q regs; C col=query,
// row=key). PV: O = P*V^T (A=P register repack, B=V from LDS; C col=dh,
// row=query -> coalesced stores). l accumulated as f32x4, reduced at end.
// ---------------------------------------------------------------------------
__global__ __launch_bounds__(256) void attn_kernel(
    const unsigned short* __restrict__ Qb, const unsigned short* __restrict__ Kb,
    const unsigned short* __restrict__ Vt, const float* __restrict__ qmask,
    const float* __restrict__ kmask, const float* __restrict__ queries,
    float* __restrict__ out) {
  __shared__ unsigned short Ksm[2][4096];  // [buf][row=key][64 dh], swizzled
  __shared__ unsigned short Vsm[2][4096];  // [buf][row=dh][64 key-perm], swizzled

  int hb = blockIdx.x;
  int qt = blockIdx.y;
  int h = hb >> 2, b = hb & 3;
  int q0 = qt * 128;
  int tid = threadIdx.x;
  int w = tid >> 6, lane = tid & 63;
  int mrow = lane & 15, quad = lane >> 4;

  // staging thread mapping: row r = j*32 + (tid>>3), slot s = tid&7,
  // fetches global chunk c = s ^ (r&7); LDS offset = j*2048 + tid*8 (shorts)
  int srow = tid >> 3, sslot = tid & 7;
  const unsigned short* kgbase =
      Kb + (b * 2048 + srow) * 512 + h * 64 + (sslot ^ (srow & 7)) * 8;
  const unsigned short* vgbase =
      Vt + (hb * 64 + srow) * 2048 + (sslot ^ (srow & 7)) * 8;
  // (row+32 keeps r&7, so the j=1 round just offsets the global row by 32)

  // Q B-frags [n=query qn*16+mrow][k=dh kh*32+quad*8]
  bf16x8 qf[2][2];
  {
    const unsigned short* qp =
        Qb + (b * 2048 + q0 + w * 32 + mrow) * 512 + h * 64 + quad * 8;
#pragma unroll
    for (int qn = 0; qn < 2; ++qn) {
      qf[qn][0] = ld_bf8(qp + qn * 8192);
      qf[qn][1] = ld_bf8(qp + qn * 8192 + 32);
    }
  }

  f32x4 zero = {0.f, 0.f, 0.f, 0.f};
  f32x4 oacc[4][2];  // [dt][qn]: col=dh dt*16+mrow, row=query quad*4+r
#pragma unroll
  for (int i = 0; i < 4; ++i) {
    oacc[i][0] = zero;
    oacc[i][1] = zero;
  }
  f32x4 lvec[2] = {zero, zero};

  // fragment-read swizzled bases (shorts): row*64 + (chunk ^ (mrow&7))*8
  const int mlow = mrow & 7;
  const float* kmB = kmask + b * 2048 + quad * 4;

  // preload chunk 0 into buf 0
  g2l16(kgbase, &Ksm[0][tid * 8]);
  g2l16(kgbase + 32 * 512, &Ksm[0][2048 + tid * 8]);
  g2l16(vgbase, &Vsm[0][tid * 8]);
  g2l16(vgbase + 32 * 2048, &Vsm[0][2048 + tid * 8]);

  for (int it = 0; it < 32; ++it) {
    int bi = it & 1;
    int kb = it * 64;
    __syncthreads();  // staged buf[bi] ready; previous compute done

    // key mask for this wave's lanes: keys kb + mt*16 + quad*4 + r
    f32x4 kmv[4];
#pragma unroll
    for (int mt = 0; mt < 4; ++mt)
      kmv[mt] = *(const f32x4*)(kmB + kb + mt * 16);

    // K A-frags and V B-frags from LDS (swizzled, conflict-free)
    bf16x8 kf[4][2], vf[4][2];
#pragma unroll
    for (int mt = 0; mt < 4; ++mt) {
#pragma unroll
      for (int kh = 0; kh < 2; ++kh)
        kf[mt][kh] = ld_bf8(
            &Ksm[bi][(mt * 16 + mrow) * 64 + ((kh * 4 + quad) ^ mlow) * 8]);
    }
#pragma unroll
    for (int dt = 0; dt < 4; ++dt) {
#pragma unroll
      for (int kg = 0; kg < 2; ++kg)
        vf[dt][kg] = ld_bf8(
            &Vsm[bi][(dt * 16 + mrow) * 64 + ((kg * 4 + quad) ^ mlow) * 8]);
    }

    // QK^T: S^T tiles [64 key x 32 q]
    f32x4 sacc[4][2];
#pragma unroll
    for (int mt = 0; mt < 4; ++mt)
#pragma unroll
      for (int qn = 0; qn < 2; ++qn) {
        f32x4 s = mfma16(kf[mt][0], qf[qn][0], zero);
        sacc[mt][qn] = mfma16(kf[mt][1], qf[qn][1], s);
      }

    // softmax (max-free, exp2 domain) + pack to P A-frags + PV
#pragma unroll
    for (int qn = 0; qn < 2; ++qn) {
      f32x4 p[4];
#pragma unroll
      for (int mt = 0; mt < 4; ++mt) {
#pragma unroll
        for (int r = 0; r < 4; ++r)
          p[mt][r] = EXP2F(sacc[mt][qn][r]) * kmv[mt][r];
        lvec[qn] += p[mt];
      }
      bf16x8 pf0 = __builtin_bit_cast(
          bf16x8, make_uint4(pk2(p[0][0], p[0][1]), pk2(p[0][2], p[0][3]),
                             pk2(p[1][0], p[1][1]), pk2(p[1][2], p[1][3])));
      bf16x8 pf1 = __builtin_bit_cast(
          bf16x8, make_uint4(pk2(p[2][0], p[2][1]), pk2(p[2][2], p[2][3]),
                             pk2(p[3][0], p[3][1]), pk2(p[3][2], p[3][3])));
#pragma unroll
      for (int dt = 0; dt < 4; ++dt) {
        oacc[dt][qn] = mfma16(pf0, vf[dt][0], oacc[dt][qn]);
        oacc[dt][qn] = mfma16(pf1, vf[dt][1], oacc[dt][qn]);
      }
    }

    if (it < 31) {
      __syncthreads();  // all waves done reading buf[1-bi]'s previous contents
      int nkb = kb + 64;
      int nbi = 1 - bi;
      g2l16(kgbase + nkb * 512, &Ksm[nbi][tid * 8]);
      g2l16(kgbase + (nkb + 32) * 512, &Ksm[nbi][2048 + tid * 8]);
      g2l16(vgbase + nkb, &Vsm[nbi][tid * 8]);
      g2l16(vgbase + nkb + 32 * 2048, &Vsm[nbi][2048 + tid * 8]);
    }
  }

  // --- epilogue: l per query (query = mrow within qn tile), then broadcast
  float linv[2];
#pragma unroll
  for (int qn = 0; qn < 2; ++qn) {
    float l = lvec[qn][0] + lvec[qn][1] + lvec[qn][2] + lvec[qn][3];
    l += __shfl_xor(l, 16);
    l += __shfl_xor(l, 32);
    int qg = b * 2048 + q0 + w * 32 + qn * 16 + mrow;
    linv[qn] = qmask[qg] / l;
  }

  // --- store: row=query quad*4+r, col=dh dt*16+mrow (coalesced dwords)
#pragma unroll
  for (int qn = 0; qn < 2; ++qn) {
#pragma unroll
    for (int r = 0; r < 4; ++r) {
      float iv = __shfl(linv[qn], quad * 4 + r);
      int qg = b * 2048 + q0 + w * 32 + qn * 16 + quad * 4 + r;
#pragma unroll
      for (int dt = 0; dt < 4; ++dt) {
        int idx = qg * 512 + h * 64 + dt * 16 + mrow;
        out[idx] = oacc[dt][qn][r] * iv + queries[idx];
      }
    }
  }
}

// ---------------------------------------------------------------------------
// Kernel 5: LayerNorm (unbiased std, eps added to std), in-place on d_out.
// ---------------------------------------------------------------------------
__global__ __launch_bounds__(256) void ln_kernel(float* __restrict__ out,
                                                 const float* __restrict__ gamma,
                                                 const float* __restrict__ beta) {
  int row = blockIdx.x * 4 + (threadIdx.x >> 6);
  int lane = threadIdx.x & 63;
  float* p = out + row * 512;
  float4 v1 = ((const float4*)p)[lane];
  float4 v2 = ((const float4*)p)[64 + lane];
  float s = v1.x + v1.y + v1.z + v1.w + v2.x + v2.y + v2.z + v2.w;
  float sq = v1.x * v1.x + v1.y * v1.y + v1.z * v1.z + v1.w * v1.w +
             v2.x * v2.x + v2.y * v2.y + v2.z * v2.z + v2.w * v2.w;
#pragma unroll
  for (int off = 32; off > 0; off >>= 1) {
    s += __shfl_xor(s, off);
    sq += __shfl_xor(sq, off);
  }
  float mean = s * (1.f / 512.f);
  float var = fmaxf((sq - 512.f * mean * mean) * (1.f / 511.f), 0.f);
  float inv = 1.f / (sqrtf(var) + 1e-8f);
  float4 g1 = ((const float4*)gamma)[lane];
  float4 g2 = ((const float4*)gamma)[64 + lane];
  float4 b1 = ((const float4*)beta)[lane];
  float4 b2 = ((const float4*)beta)[64 + lane];
  v1.x = g1.x * (v1.x - mean) * inv + b1.x;
  v1.y = g1.y * (v1.y - mean) * inv + b1.y;
  v1.z = g1.z * (v1.z - mean) * inv + b1.z;
  v1.w = g1.w * (v1.w - mean) * inv + b1.w;
  v2.x = g2.x * (v2.x - mean) * inv + b2.x;
  v2.y = g2.y * (v2.y - mean) * inv + b2.y;
  v2.z = g2.z * (v2.z - mean) * inv + b2.z;
  v2.w = g2.w * (v2.w - mean) * inv + b2.w;
  ((float4*)p)[lane] = v1;
  ((float4*)p)[64 + lane] = v2;
}

// ---------------------------------------------------------------------------
extern "C" void kernel_launch(void* const* d_in, const int* in_sizes, int n_in,
                              void* d_out, int out_size, void* d_ws, size_t ws_size,
                              hipStream_t stream) {
  (void)in_sizes; (void)n_in; (void)out_size; (void)ws_size;
  const float* queries = (const float*)d_in[0];
  const float* keys    = (const float*)d_in[1];
  const float* values  = (const float*)d_in[2];
  const float* Wq = (const float*)d_in[3];
  const float* bq = (const float*)d_in[4];
  const float* Wk = (const float*)d_in[5];
  const float* bk = (const float*)d_in[6];
  const float* Wv = (const float*)d_in[7];
  const float* bv = (const float*)d_in[8];
  const float* gamma = (const float*)d_in[9];
  const float* beta  = (const float*)d_in[10];
  float* out = (float*)d_out;

  char* ws = (char*)d_ws;
  unsigned short* Qb = (unsigned short*)(ws);                    // 8 MB
  unsigned short* Kb = (unsigned short*)(ws + 8 * 1024 * 1024);  // 8 MB
  unsigned short* Vt = (unsigned short*)(ws + 16 * 1024 * 1024); // 8 MB
  unsigned short* Wt = (unsigned short*)(ws + 24 * 1024 * 1024); // 1.5 MB
  float* qmask = (float*)(ws + 24 * 1024 * 1024 + 3 * 512 * 512 * 2);
  float* kmask = qmask + 8192;

  wt_kernel<<<384, 256, 0, stream>>>(Wq, Wk, Wv, Wt);
  mask_kernel<<<4096, 256, 0, stream>>>(queries, keys, qmask, kmask);
  proj_kernel<<<dim3(192, 4), 256, 0, stream>>>(queries, keys, values, bq, bk, bv,
                                                Wt, Qb, Kb, Vt);
  attn_kernel<<<dim3(32, 16), 256, 0, stream>>>(Qb, Kb, Vt, qmask, kmask, queries, out);
  ln_kernel<<<2048, 256, 0, stream>>>(out, gamma, beta);
}

// Round 7
// 190.514 us; speedup vs baseline: 1.2529x; 1.0560x over previous
//
#include <hip/hip_runtime.h>

// R7: attn: 128-key chunks with ONE barrier per chunk (17 barriers/block vs
// R6's 64 -- each barrier's vmcnt(0) drain now has a full chunk of compute
// in flight), 2x2 wave split (q-half x key-half) halving LDS read traffic,
// epilogue cross-wave combine through LDS aliased onto the dead staging
// buffers. mask_kernel fused into proj (row sums from staged fp32 A-tiles).

typedef __attribute__((ext_vector_type(8))) __bf16 bf16x8;
typedef __attribute__((ext_vector_type(4))) float f32x4;

#if __has_builtin(__builtin_amdgcn_exp2f)
#define EXP2F __builtin_amdgcn_exp2f
#else
#define EXP2F exp2f
#endif

#define QSCALE (0.125f * 1.4426950408889634f)  // fold /sqrt(64) and ln->log2

__device__ __forceinline__ unsigned short f2bf(float f) {
  return __builtin_bit_cast(unsigned short, (__bf16)f);
}
__device__ __forceinline__ unsigned pk2(float a, float b) {
  return (unsigned)f2bf(a) | ((unsigned)f2bf(b) << 16);
}
__device__ __forceinline__ f32x4 mfma16(bf16x8 a, bf16x8 b, f32x4 c) {
  return __builtin_amdgcn_mfma_f32_16x16x32_bf16(a, b, c, 0, 0, 0);
}
__device__ __forceinline__ bf16x8 ld_bf8(const unsigned short* p) {
  return *(const bf16x8*)p;
}
// async global->LDS, 16 B per lane; LDS dst is wave-uniform base + lane*16
__device__ __forceinline__ void g2l16(const void* g, void* l) {
  __builtin_amdgcn_global_load_lds(
      (const __attribute__((address_space(1))) void*)g,
      (__attribute__((address_space(3))) void*)l, 16, 0, 0);
}

// ---------------------------------------------------------------------------
// Kernel 1: transpose + convert the three 512x512 weight matrices to bf16,
// layout Wt[z][n][k] (n-major) so MFMA B-fragments read contiguous k.
// ---------------------------------------------------------------------------
__global__ __launch_bounds__(256) void wt_kernel(const float* __restrict__ Wq,
                                                 const float* __restrict__ Wk,
                                                 const float* __restrict__ Wv,
                                                 unsigned short* __restrict__ Wt) {
  int idx = blockIdx.x * 256 + threadIdx.x;
  int o = idx * 8;
  int z = o >> 18;
  int rem = o & 262143;
  int n = rem >> 9;
  int k0 = rem & 511;
  const float* W = (z == 0) ? Wq : ((z == 1) ? Wk : Wv);
  unsigned int w[4];
#pragma unroll
  for (int i = 0; i < 4; ++i) {
    unsigned short lo = f2bf(W[(k0 + 2 * i) * 512 + n]);
    unsigned short hi = f2bf(W[(k0 + 2 * i + 1) * 512 + n]);
    w[i] = (unsigned)lo | ((unsigned)hi << 16);
  }
  *(uint4*)(Wt + o) = make_uint4(w[0], w[1], w[2], w[3]);
}

// ---------------------------------------------------------------------------
// Kernel 2: QKV projection as m97-style GEMM + fused padding-mask compute.
// Grid (192 m-blocks, 4 n-blocks); z = m-block/64. Tile 128x128, BK=32.
// Blocks with n0==0 && z<2 also accumulate raw-X row sums from the staged
// fp32 A-tiles (wn==0 waves) and write qmask/kmask (saves a 32-MB kernel).
// V stored transposed with the permuted intra-32-key order
// (pos = quad*8 + sub*4 + r), matching attn's P register-repack k-order.
// ---------------------------------------------------------------------------
__global__ __launch_bounds__(256, 3) void proj_kernel(
    const float* __restrict__ Xq, const float* __restrict__ Xk,
    const float* __restrict__ Xv, const float* __restrict__ bq,
    const float* __restrict__ bk, const float* __restrict__ bv,
    const unsigned short* __restrict__ Wt, unsigned short* __restrict__ Qb,
    unsigned short* __restrict__ Kb, unsigned short* __restrict__ Vt,
    float* __restrict__ qmask, float* __restrict__ kmask) {
  __shared__ float Asm[2][128][16];
  __shared__ unsigned short Bsm[128][32];

  int tid = threadIdx.x;
  int m0g = blockIdx.x * 128;
  int z = m0g >> 13;
  int m0 = m0g & 8191;
  int n0 = blockIdx.y * 128;
  const float* X = (z == 0) ? Xq : ((z == 1) ? Xk : Xv);
  const float* bias = (z == 0) ? bq : ((z == 1) ? bk : bv);
  const unsigned short* Wz = Wt + z * 262144;

  int w = tid >> 6, lane = tid & 63;
  int wm = w >> 1, wn = w & 1;
  int mrow = lane & 15, quad = lane >> 4;

  int srow = tid >> 2, schk = tid & 3;
  const float* gA = X + (m0 + srow) * 512 + schk * 4;
  const unsigned short* gB = Wz + (n0 + srow) * 512 + schk * 8;
  char* lA = (char*)&Asm[0][0][0] + tid * 16;
  char* lB = (char*)&Bsm[0][0] + tid * 16;

  const float* rA = &Asm[quad >> 1][0][(quad & 1) * 8];
  const unsigned short* rB = &Bsm[0][quad * 8];

  f32x4 zero = {0.f, 0.f, 0.f, 0.f};
  f32x4 acc[4][4];
#pragma unroll
  for (int i = 0; i < 4; ++i)
#pragma unroll
    for (int j = 0; j < 4; ++j) acc[i][j] = zero;

  bool domask = (z < 2) && (n0 == 0) && (wn == 0);
  float rsum[4] = {0.f, 0.f, 0.f, 0.f};

  for (int kc = 0; kc < 16; ++kc) {
    int ko = kc * 32;
    g2l16(gA + ko, lA);
    g2l16(gA + ko + 64 * 512, lA + 4096);
    g2l16(gA + ko + 16, lA + 8192);
    g2l16(gA + ko + 16 + 64 * 512, lA + 12288);
    g2l16(gB + ko, lB);
    g2l16(gB + ko + 64 * 512, lB + 4096);
    __syncthreads();

    bf16x8 af[4], bfr[4];
#pragma unroll
    for (int mt = 0; mt < 4; ++mt) {
      const float* pa = rA + (wm * 64 + mt * 16 + mrow) * 16;
      f32x4 lo = *(const f32x4*)pa;
      f32x4 hi = *(const f32x4*)(pa + 4);
      if (domask)
        rsum[mt] += lo[0] + lo[1] + lo[2] + lo[3] + hi[0] + hi[1] + hi[2] + hi[3];
      bf16x8 t;
      t[0] = (__bf16)lo[0]; t[1] = (__bf16)lo[1];
      t[2] = (__bf16)lo[2]; t[3] = (__bf16)lo[3];
      t[4] = (__bf16)hi[0]; t[5] = (__bf16)hi[1];
      t[6] = (__bf16)hi[2]; t[7] = (__bf16)hi[3];
      af[mt] = t;
    }
#pragma unroll
    for (int nt = 0; nt < 4; ++nt)
      bfr[nt] = ld_bf8(rB + (wn * 64 + nt * 16 + mrow) * 32);
#pragma unroll
    for (int mt = 0; mt < 4; ++mt)
#pragma unroll
      for (int nt = 0; nt < 4; ++nt)
        acc[mt][nt] = mfma16(af[mt], bfr[nt], acc[mt][nt]);
    __syncthreads();
  }

  if (domask) {
    float* msk = (z == 0) ? qmask : kmask;
#pragma unroll
    for (int mt = 0; mt < 4; ++mt) {
      float s = rsum[mt];
      s += __shfl_xor(s, 16);
      s += __shfl_xor(s, 32);
      if (quad == 0)
        msk[m0 + wm * 64 + mt * 16 + mrow] = (s == 0.f) ? 0.f : 1.f;
    }
  }

  if (z < 2) {
    unsigned short* dst = (z == 0) ? Qb : Kb;
    float sc = (z == 0) ? QSCALE : 1.0f;
#pragma unroll
    for (int nt = 0; nt < 4; ++nt) {
      int n = n0 + wn * 64 + nt * 16 + mrow;
      float bv_ = bias[n];
#pragma unroll
      for (int mt = 0; mt < 4; ++mt) {
        int m = m0 + wm * 64 + mt * 16 + quad * 4;
#pragma unroll
        for (int r = 0; r < 4; ++r) {
          float v = fmaxf(acc[mt][nt][r] + bv_, 0.f) * sc;
          dst[(m + r) * 512 + n] = f2bf(v);
        }
      }
    }
  } else {
    // V: permuted-transposed store (pos = quad*8 + (mt&1)*4 + r in 32-t group)
#pragma unroll
    for (int nt = 0; nt < 4; ++nt) {
      int n = n0 + wn * 64 + nt * 16 + mrow;
      int hh = n >> 6, jj = n & 63;
      float bv_ = bias[n];
#pragma unroll
      for (int mt = 0; mt < 4; ++mt) {
        int grow = m0 + wm * 64 + mt * 16 + quad * 4;
        int bb = grow >> 11, tl = grow & 2047;
        int pos = (tl & ~31) + quad * 8 + (mt & 1) * 4;
        float p0 = fmaxf(acc[mt][nt][0] + bv_, 0.f);
        float p1 = fmaxf(acc[mt][nt][1] + bv_, 0.f);
        float p2 = fmaxf(acc[mt][nt][2] + bv_, 0.f);
        float p3 = fmaxf(acc[mt][nt][3] + bv_, 0.f);
        *(uint2*)(Vt + ((hh * 4 + bb) * 64 + jj) * 2048 + pos) =
            make_uint2(pk2(p0, p1), pk2(p2, p3));
      }
    }
  }
}

// ---------------------------------------------------------------------------
// Kernel 3: attention. Grid (hb=32, qt=16); block = 128 q, 4 waves in 2x2:
// qh = wave>>1 owns 64 queries, kh2 = wave&1 owns the 64-key half of each
// 128-key chunk. 16 chunks, ONE barrier per chunk, double-buffered K/V LDS
// (2 x 32 KB) staged via g2l16 with XOR swizzle. QK: S^T = K*Q^T. PV:
// O = P*V^T with P as A-operand (register repack, Vt permuted to match);
// C-layout col=dh -> coalesced stores. Epilogue: cross-wave (kh2) O/l
// combine through LDS aliased onto the staging buffers.
// ---------------------------------------------------------------------------
__global__ __launch_bounds__(256, 2) void attn_kernel(
    const unsigned short* __restrict__ Qb, const unsigned short* __restrict__ Kb,
    const unsigned short* __restrict__ Vt, const float* __restrict__ qmask,
    const float* __restrict__ kmask, const float* __restrict__ queries,
    float* __restrict__ out) {
  __shared__ char smem[66560];
  unsigned short* KsmS = (unsigned short*)smem;            // [2][8192] shorts
  unsigned short* VsmS = (unsigned short*)(smem + 32768);  // [2][8192] shorts
  float* Obuf = (float*)smem;                              // [128][65] alias
  float* lbuf = (float*)(smem + 65536);                    // [2][128]

  int hb = blockIdx.x;
  int qt = blockIdx.y;
  int h = hb >> 2, b = hb & 3;
  int q0 = qt * 128;
  int tid = threadIdx.x;
  int w = tid >> 6, lane = tid & 63;
  int qh = w >> 1, kh2 = w & 1;
  int mrow = lane & 15, quad = lane >> 4;

  // staging source pointers (XOR-swizzled slot->chunk)
  const unsigned short* gK =
      Kb + (b * 2048 + (tid >> 3)) * 512 + h * 64 + (((tid & 7) ^ ((tid >> 3) & 7)) * 8);
  const unsigned short* gV =
      Vt + (hb * 64 + (tid >> 4)) * 2048 + (((tid & 15) ^ ((tid >> 4) & 15)) * 8);

  // Q B-frags [n=q qn*16+mrow][k=dh kh*32+quad*8]
  bf16x8 qf[4][2];
  {
    const unsigned short* qp =
        Qb + (b * 2048 + q0 + qh * 64 + mrow) * 512 + h * 64 + quad * 8;
#pragma unroll
    for (int qn = 0; qn < 4; ++qn) {
      qf[qn][0] = ld_bf8(qp + qn * 8192);
      qf[qn][1] = ld_bf8(qp + qn * 8192 + 32);
    }
  }

  f32x4 zero = {0.f, 0.f, 0.f, 0.f};
  f32x4 oacc[4][4];  // [dt][qn]: col=dh dt*16+mrow, row=q quad*4+r
#pragma unroll
  for (int i = 0; i < 4; ++i)
#pragma unroll
    for (int j = 0; j < 4; ++j) oacc[i][j] = zero;
  float lpart[4] = {0.f, 0.f, 0.f, 0.f};

  const float* kmB = kmask + b * 2048 + kh2 * 64 + quad * 4;
  const int kfrow = kh2 * 64;          // key-row base in Ksm
  const int mlow = mrow & 7;

  // preload chunk 0 into buf 0
#pragma unroll
  for (int j = 0; j < 4; ++j) {
    g2l16(gK + j * 32 * 512, &KsmS[j * 2048 + tid * 8]);
    g2l16(gV + j * 16 * 2048, &VsmS[j * 2048 + tid * 8]);
  }

  for (int it = 0; it < 16; ++it) {
    int bi = it & 1;
    int kb = it * 128;
    __syncthreads();  // drains each wave's own staging DMA; buf bi ready

    if (it < 15) {
      int nkb = kb + 128;
      int nb = 1 - bi;
#pragma unroll
      for (int j = 0; j < 4; ++j) {
        g2l16(gK + (nkb + j * 32) * 512, &KsmS[nb * 8192 + j * 2048 + tid * 8]);
        g2l16(gV + nkb + j * 16 * 2048, &VsmS[nb * 8192 + j * 2048 + tid * 8]);
      }
    }

    // key mask for this wave's lanes
    f32x4 kmv[4];
#pragma unroll
    for (int mt = 0; mt < 4; ++mt)
      kmv[mt] = *(const f32x4*)(kmB + kb + mt * 16);

#pragma unroll
    for (int kg = 0; kg < 2; ++kg) {
      // K A-frags for mt = 2kg, 2kg+1 ; V B-frags for this 32-key group
      bf16x8 kfA0 = ld_bf8(&KsmS[bi * 8192 + (kfrow + kg * 32 + mrow) * 64 +
                                 ((quad) ^ mlow) * 8]);
      bf16x8 kfA1 = ld_bf8(&KsmS[bi * 8192 + (kfrow + kg * 32 + mrow) * 64 +
                                 ((4 + quad) ^ mlow) * 8]);
      bf16x8 kfB0 = ld_bf8(&KsmS[bi * 8192 + (kfrow + kg * 32 + 16 + mrow) * 64 +
                                 ((quad) ^ mlow) * 8]);
      bf16x8 kfB1 = ld_bf8(&KsmS[bi * 8192 + (kfrow + kg * 32 + 16 + mrow) * 64 +
                                 ((4 + quad) ^ mlow) * 8]);
      bf16x8 vfg[4];
#pragma unroll
      for (int dt = 0; dt < 4; ++dt)
        vfg[dt] = ld_bf8(&VsmS[bi * 8192 + (dt * 16 + mrow) * 128 +
                               ((kh2 * 8 + kg * 4 + quad) ^ mrow) * 8]);

      f32x4 sA[4], sB[4];
#pragma unroll
      for (int qn = 0; qn < 4; ++qn) {
        f32x4 s0 = mfma16(kfA0, qf[qn][0], zero);
        sA[qn] = mfma16(kfA1, qf[qn][1], s0);
        f32x4 s1 = mfma16(kfB0, qf[qn][0], zero);
        sB[qn] = mfma16(kfB1, qf[qn][1], s1);
      }
#pragma unroll
      for (int qn = 0; qn < 4; ++qn) {
        f32x4 p0, p1;
#pragma unroll
        for (int r = 0; r < 4; ++r) {
          p0[r] = EXP2F(sA[qn][r]) * kmv[kg * 2][r];
          p1[r] = EXP2F(sB[qn][r]) * kmv[kg * 2 + 1][r];
        }
        lpart[qn] += p0[0] + p0[1] + p0[2] + p0[3] + p1[0] + p1[1] + p1[2] + p1[3];
        bf16x8 pf = __builtin_bit_cast(
            bf16x8, make_uint4(pk2(p0[0], p0[1]), pk2(p0[2], p0[3]),
                               pk2(p1[0], p1[1]), pk2(p1[2], p1[3])));
#pragma unroll
        for (int dt = 0; dt < 4; ++dt)
          oacc[dt][qn] = mfma16(pf, vfg[dt], oacc[dt][qn]);
      }
    }
  }

  // --- epilogue: reduce l over quads; combine kh2 halves through LDS
#pragma unroll
  for (int qn = 0; qn < 4; ++qn) {
    lpart[qn] += __shfl_xor(lpart[qn], 16);
    lpart[qn] += __shfl_xor(lpart[qn], 32);
  }
  __syncthreads();  // all staging reads done; smem reusable
  if (quad == 0) {
#pragma unroll
    for (int qn = 0; qn < 4; ++qn)
      lbuf[kh2 * 128 + qh * 64 + qn * 16 + mrow] = lpart[qn];
  }
  if (kh2 == 1) {
#pragma unroll
    for (int dt = 0; dt < 4; ++dt)
#pragma unroll
      for (int qn = 0; qn < 4; ++qn)
#pragma unroll
        for (int r = 0; r < 4; ++r)
          Obuf[(qh * 64 + qn * 16 + quad * 4 + r) * 65 + dt * 16 + mrow] =
              oacc[dt][qn][r];
  }
  __syncthreads();
  if (kh2 == 0) {
#pragma unroll
    for (int qn = 0; qn < 4; ++qn) {
#pragma unroll
      for (int r = 0; r < 4; ++r) {
        int qrow = qh * 64 + qn * 16 + quad * 4 + r;
        float l = lbuf[qrow] + lbuf[128 + qrow];
        int qg = b * 2048 + q0 + qrow;
        float inv = qmask[qg] / l;
#pragma unroll
        for (int dt = 0; dt < 4; ++dt) {
          int idx = qg * 512 + h * 64 + dt * 16 + mrow;
          out[idx] =
              (oacc[dt][qn][r] + Obuf[qrow * 65 + dt * 16 + mrow]) * inv +
              queries[idx];
        }
      }
    }
  }
}

// ---------------------------------------------------------------------------
// Kernel 4: LayerNorm (unbiased std, eps added to std), in-place on d_out.
// ---------------------------------------------------------------------------
__global__ __launch_bounds__(256) void ln_kernel(float* __restrict__ out,
                                                 const float* __restrict__ gamma,
                                                 const float* __restrict__ beta) {
  int row = blockIdx.x * 4 + (threadIdx.x >> 6);
  int lane = threadIdx.x & 63;
  float* p = out + row * 512;
  float4 v1 = ((const float4*)p)[lane];
  float4 v2 = ((const float4*)p)[64 + lane];
  float s = v1.x + v1.y + v1.z + v1.w + v2.x + v2.y + v2.z + v2.w;
  float sq = v1.x * v1.x + v1.y * v1.y + v1.z * v1.z + v1.w * v1.w +
             v2.x * v2.x + v2.y * v2.y + v2.z * v2.z + v2.w * v2.w;
#pragma unroll
  for (int off = 32; off > 0; off >>= 1) {
    s += __shfl_xor(s, off);
    sq += __shfl_xor(sq, off);
  }
  float mean = s * (1.f / 512.f);
  float var = fmaxf((sq - 512.f * mean * mean) * (1.f / 511.f), 0.f);
  float inv = 1.f / (sqrtf(var) + 1e-8f);
  float4 g1 = ((const float4*)gamma)[lane];
  float4 g2 = ((const float4*)gamma)[64 + lane];
  float4 b1 = ((const float4*)beta)[lane];
  float4 b2 = ((const float4*)beta)[64 + lane];
  v1.x = g1.x * (v1.x - mean) * inv + b1.x;
  v1.y = g1.y * (v1.y - mean) * inv + b1.y;
  v1.z = g1.z * (v1.z - mean) * inv + b1.z;
  v1.w = g1.w * (v1.w - mean) * inv + b1.w;
  v2.x = g2.x * (v2.x - mean) * inv + b2.x;
  v2.y = g2.y * (v2.y - mean) * inv + b2.y;
  v2.z = g2.z * (v2.z - mean) * inv + b2.z;
  v2.w = g2.w * (v2.w - mean) * inv + b2.w;
  ((float4*)p)[lane] = v1;
  ((float4*)p)[64 + lane] = v2;
}

// ---------------------------------------------------------------------------
extern "C" void kernel_launch(void* const* d_in, const int* in_sizes, int n_in,
                              void* d_out, int out_size, void* d_ws, size_t ws_size,
                              hipStream_t stream) {
  (void)in_sizes; (void)n_in; (void)out_size; (void)ws_size;
  const float* queries = (const float*)d_in[0];
  const float* keys    = (const float*)d_in[1];
  const float* values  = (const float*)d_in[2];
  const float* Wq = (const float*)d_in[3];
  const float* bq = (const float*)d_in[4];
  const float* Wk = (const float*)d_in[5];
  const float* bk = (const float*)d_in[6];
  const float* Wv = (const float*)d_in[7];
  const float* bv = (const float*)d_in[8];
  const float* gamma = (const float*)d_in[9];
  const float* beta  = (const float*)d_in[10];
  float* out = (float*)d_out;

  char* ws = (char*)d_ws;
  unsigned short* Qb = (unsigned short*)(ws);                    // 8 MB
  unsigned short* Kb = (unsigned short*)(ws + 8 * 1024 * 1024);  // 8 MB
  unsigned short* Vt = (unsigned short*)(ws + 16 * 1024 * 1024); // 8 MB
  unsigned short* Wt = (unsigned short*)(ws + 24 * 1024 * 1024); // 1.5 MB
  float* qmask = (float*)(ws + 24 * 1024 * 1024 + 3 * 512 * 512 * 2);
  float* kmask = qmask + 8192;

  wt_kernel<<<384, 256, 0, stream>>>(Wq, Wk, Wv, Wt);
  proj_kernel<<<dim3(192, 4), 256, 0, stream>>>(queries, keys, values, bq, bk, bv,
                                                Wt, Qb, Kb, Vt, qmask, kmask);
  attn_kernel<<<dim3(32, 16), 256, 0, stream>>>(Qb, Kb, Vt, qmask, kmask, queries, out);
  ln_kernel<<<2048, 256, 0, stream>>>(out, gamma, beta);
}